// Round 2
// baseline (214.587 us; speedup 1.0000x reference)
//
#include <hip/hip_runtime.h>
#include <math.h>

#define BB 8
#define SS 1024
#define DD 768
#define HH 12
#define DHH 64
#define BSS (BB*SS)          // 8192
#define NQKV 2304            // stacked Q|K|V output columns
#define NT 24                // 768 / BK(=32) K-tiles

typedef _Float16 half8 __attribute__((ext_vector_type(8)));
typedef _Float16 half4 __attribute__((ext_vector_type(4)));
typedef float    f32x4 __attribute__((ext_vector_type(4)));

// Async global->LDS DMA, 16 B/lane. LDS dest = wave-uniform base + lane*16.
__device__ __forceinline__ void glds16(const _Float16* g, _Float16* l)
{
    __builtin_amdgcn_global_load_lds(
        (const __attribute__((address_space(1))) uint32_t*)(g),
        (__attribute__((address_space(3))) uint32_t*)(l),
        16, 0, 0);
}

// ---------------------------------------------------------------------------
// prep: one launch doing x cast (blocks 0..3071) and all 4 weight
// transposes (blocks 3072..3647).  (unchanged)
// ---------------------------------------------------------------------------
__global__ __launch_bounds__(256)
void prep(const float* __restrict__ x, _Float16* __restrict__ xh,
          const float* __restrict__ Wq, const float* __restrict__ Wk,
          const float* __restrict__ Wv, const float* __restrict__ Wo,
          _Float16* __restrict__ Wt, _Float16* __restrict__ Wot)
{
    const int blk = blockIdx.x;
    const int tid = threadIdx.x;

    if (blk < 3072) {                    // ---- cast x -> f16 ----
        int i = blk * 256 + tid;
        const float4* xp = (const float4*)x + (size_t)i * 2;
        float4 u = xp[0], v = xp[1];
        half8 h = { (_Float16)u.x, (_Float16)u.y, (_Float16)u.z, (_Float16)u.w,
                    (_Float16)v.x, (_Float16)v.y, (_Float16)v.z, (_Float16)v.w };
        ((half8*)xh)[i] = h;
        return;
    }

    // ---- weight transpose: 576 tiles = (12 d0) x (12 n) x (4 z) ----
    __shared__ float T[64][65];
    const int t  = blk - 3072;
    const int z  = t / 144;              // 0..3
    const int r_ = t - z * 144;
    const int d0 = (r_ / 12) * 64;
    const int n_outer = r_ % 12;

    const float* src;
    _Float16* dst;
    int base_mul, row_stride;
    if (z < 3) {
        src = (z == 0) ? Wq : (z == 1) ? Wk : Wv;
        dst = Wt + (size_t)z * DD * DD;
        base_mul = DD * DHH; row_stride = DHH;
    } else {
        src = Wo; dst = Wot;
        base_mul = 64; row_stride = DD;
    }

    const size_t base = (size_t)n_outer * base_mul;
    {
        int dl = tid >> 2, c0 = (tid & 3) * 16;
        const float* p = src + base + (size_t)(d0 + dl) * row_stride + c0;
#pragma unroll
        for (int m = 0; m < 4; ++m) {
            float4 f = *(const float4*)(p + m * 4);
            T[dl][c0 + m*4 + 0] = f.x;
            T[dl][c0 + m*4 + 1] = f.y;
            T[dl][c0 + m*4 + 2] = f.z;
            T[dl][c0 + m*4 + 3] = f.w;
        }
    }
    __syncthreads();
    {
        int e = tid >> 2, c = tid & 3;
        half8 lo, hi;
#pragma unroll
        for (int i = 0; i < 8; ++i) {
            lo[i] = (_Float16)T[c*16 + i][e];
            hi[i] = (_Float16)T[c*16 + 8 + i][e];
        }
        _Float16* q = dst + ((size_t)n_outer * 64 + e) * DD + d0 + c * 16;
        *(half8*)q = lo;
        *(half8*)(q + 8) = hi;
    }
}

// ---------------------------------------------------------------------------
// Stacked QKV GEMM, round-10: 128x192 tile -> 64 x 12 = 768 blocks = EXACTLY
// 3 blocks/CU (no dispatch tail, 12 waves/CU cross-block TLP).  4 waves,
// wave-tile 64x96 (acc[4][6]).  BK=32, double-buffered LDS (40 KB), 2 phases
// per K-tile with HALF-PHASED staging: A split into early rows {0-31,64-95}
// (consumed in P1) / late rows {32-63,96-127} (P2); B fully consumed in P1.
// Staging schedule (per wave, 5 glds/tile):  t.P1: stage t+1.A-late;
// t.P2: stage t+2.B (3) + t+2.A-early.  Gates: vmcnt(5)+s_barrier at each
// phase end -> ~1 K-tile of load lead, never drains until the 2-tile tail.
// T2 swizzle source+read side, T5 setprio, XCD-bijective swizzle (768%8=0).
// ---------------------------------------------------------------------------
#define GATE(N) asm volatile("s_waitcnt vmcnt(" #N ")\n\ts_barrier" ::: "memory")

__global__ __launch_bounds__(256)
void gemm_qkv_128x192(const _Float16* __restrict__ Xh, const _Float16* __restrict__ Wt,
                      const float* __restrict__ bq, const float* __restrict__ bk,
                      const float* __restrict__ bv,
                      _Float16* __restrict__ qo, _Float16* __restrict__ ko,
                      _Float16* __restrict__ vto)
{
    __shared__ _Float16 Ab[2][128][32];   // 16 KB
    __shared__ _Float16 Bb[2][192][32];   // 24 KB

    const int bid = blockIdx.x;          // 0..767
    const int c8  = bid & 7;             // XCD
    const int g   = bid >> 3;            // 0..95
    const int m_t = c8 * 8 + g / 12;     // 0..63
    const int n_t = g % 12;              // 0..11
    const int m0 = m_t * 128;
    const int n0 = n_t * 192;

    const int tid  = threadIdx.x;
    const int wave = tid >> 6;           // 0..3
    const int lane = tid & 63;
    const int l16  = tid & 15;
    const int quad = (tid >> 4) & 3;
    const int wy = wave >> 1;            // 0..1 : wave tile 64x96
    const int wx = wave & 1;             // 0..1

    // T2 swizzle: inverse involution on the global source column so the
    // linear DMA lands data at swizzled LDS slots; reads use the same XOR.
    const int scol = ((lane & 3) ^ ((lane >> 3) & 3)) * 8;
    const int fcol = (quad ^ ((l16 >> 1) & 3)) * 8;

    // staging assignments (per wave): A-early chunk {0,16,64,80}[wave],
    // A-late = +32; B rows wave*48 .. +48 (3 chunks of 16).
    const int AErow = (wave & 1) * 16 + (wave >> 1) * 64;
    const int ALrow = AErow + 32;
    const int w48   = wave * 48;
    const _Float16* apE = Xh + (size_t)(m0 + AErow + (lane >> 2)) * DD + scol;
    const _Float16* apL = Xh + (size_t)(m0 + ALrow + (lane >> 2)) * DD + scol;
    const _Float16* bp0 = Wt + (size_t)(n0 + w48 + (lane >> 2)) * DD + scol;

#define STAGE_AE(buf, kt) glds16(apE + (kt) * 32, &Ab[buf][AErow][0])
#define STAGE_AL(buf, kt) glds16(apL + (kt) * 32, &Ab[buf][ALrow][0])
#define STAGE_B(buf, kt)  do {                                        \
        glds16(bp0 + (kt) * 32,            &Bb[buf][w48][0]);         \
        glds16(bp0 + 16 * DD + (kt) * 32,  &Bb[buf][w48 + 16][0]);    \
        glds16(bp0 + 32 * DD + (kt) * 32,  &Bb[buf][w48 + 32][0]);    \
    } while (0)

    f32x4 acc[4][6];
#pragma unroll
    for (int i = 0; i < 4; ++i)
#pragma unroll
        for (int j = 0; j < 6; ++j) acc[i][j] = (f32x4){0.f, 0.f, 0.f, 0.f};

    // ---- prologue: t0 fully (5), t1.B + t1.A-early (4) ----
    STAGE_AE(0, 0); STAGE_AL(0, 0); STAGE_B(0, 0);
    STAGE_B(1, 1);  STAGE_AE(1, 1);
    GATE(4);                              // t0 resident; 4 in flight

#define PHASE1(c, stg)                                                      \
    {                                                                       \
        half8 a0 = *(const half8*)&Ab[c][wy * 64 +  0 + l16][fcol];         \
        half8 a1 = *(const half8*)&Ab[c][wy * 64 + 16 + l16][fcol];         \
        _Pragma("unroll")                                                   \
        for (int j = 0; j < 6; ++j)                                         \
            bfr[j] = *(const half8*)&Bb[c][wx * 96 + j * 16 + l16][fcol];   \
        stg;                                                                \
        __builtin_amdgcn_s_setprio(1);                                      \
        _Pragma("unroll")                                                   \
        for (int j = 0; j < 6; ++j) {                                       \
            acc[0][j] = __builtin_amdgcn_mfma_f32_16x16x32_f16(a0, bfr[j], acc[0][j], 0, 0, 0); \
            acc[1][j] = __builtin_amdgcn_mfma_f32_16x16x32_f16(a1, bfr[j], acc[1][j], 0, 0, 0); \
        }                                                                   \
        __builtin_amdgcn_s_setprio(0);                                      \
    }

#define PHASE2(c, stg)                                                      \
    {                                                                       \
        half8 a2 = *(const half8*)&Ab[c][wy * 64 + 32 + l16][fcol];         \
        half8 a3 = *(const half8*)&Ab[c][wy * 64 + 48 + l16][fcol];         \
        stg;                                                                \
        __builtin_amdgcn_s_setprio(1);                                      \
        _Pragma("unroll")                                                   \
        for (int j = 0; j < 6; ++j) {                                       \
            acc[2][j] = __builtin_amdgcn_mfma_f32_16x16x32_f16(a2, bfr[j], acc[2][j], 0, 0, 0); \
            acc[3][j] = __builtin_amdgcn_mfma_f32_16x16x32_f16(a3, bfr[j], acc[3][j], 0, 0, 0); \
        }                                                                   \
        __builtin_amdgcn_s_setprio(0);                                      \
    }

    half8 bfr[6];

#pragma unroll 2
    for (int kt = 0; kt < 22; ++kt) {
        const int c = kt & 1;
        PHASE1(c, STAGE_AL(c ^ 1, kt + 1));
        GATE(5);
        PHASE2(c, { STAGE_B(c, kt + 2); STAGE_AE(c, kt + 2); });
        GATE(5);
    }
    // ---- tail: kt = 22 (buf 0), kt = 23 (buf 1) ----
    PHASE1(0, STAGE_AL(1, 23));
    GATE(5);
    PHASE2(0, );
    GATE(1);
    PHASE1(1, );
    GATE(0);
    PHASE2(1, );

#undef PHASE1
#undef PHASE2
#undef STAGE_AE
#undef STAGE_AL
#undef STAGE_B

    // ---- epilogue: n-tile entirely within Q, K, or V (192*4 = 768) ----
    const int wsel = n_t >> 2;           // 0=Q, 1=K, 2=V
    const int ncb  = (n_t & 3) * 192 + wx * 96;
    const float* bp_ = (wsel == 0) ? bq : (wsel == 1) ? bk : bv;

    float bvv[6]; int hh6[6], ee6[6];
#pragma unroll
    for (int j = 0; j < 6; ++j) {
        int nl = ncb + j * 16 + l16;
        bvv[j] = bp_[nl];
        hh6[j] = nl >> 6;
        ee6[j] = nl & 63;
    }

    if (wsel == 0) {
#pragma unroll
        for (int i = 0; i < 4; ++i)
#pragma unroll
            for (int r = 0; r < 4; ++r) {
                int row = m0 + wy * 64 + i * 16 + quad * 4 + r;
                int b_ = row >> 10;
                int s  = row & (SS - 1);
#pragma unroll
                for (int j = 0; j < 6; ++j) {
                    float val = (acc[i][j][r] + bvv[j]) * 0.125f;
                    qo[((size_t)(b_ * HH + hh6[j]) * SS + s) * DHH + ee6[j]] = (_Float16)val;
                }
            }
    } else if (wsel == 1) {
#pragma unroll
        for (int i = 0; i < 4; ++i)
#pragma unroll
            for (int r = 0; r < 4; ++r) {
                int row = m0 + wy * 64 + i * 16 + quad * 4 + r;
                int b_ = row >> 10;
                int s  = row & (SS - 1);
#pragma unroll
                for (int j = 0; j < 6; ++j) {
                    float val = acc[i][j][r] + bvv[j];
                    ko[((size_t)(b_ * HH + hh6[j]) * SS + s) * DHH + ee6[j]] = (_Float16)val;
                }
            }
    } else {
#pragma unroll
        for (int i = 0; i < 4; ++i)
#pragma unroll
            for (int r = 0; r < 4; ++r) {
                int row = m0 + wy * 64 + i * 16 + quad * 4 + r;
                int b_ = row >> 10;
                int s  = row & (SS - 1);
#pragma unroll
                for (int j = 0; j < 6; ++j) {
                    float val = acc[i][j][r] + bvv[j];
                    vto[((size_t)(b_ * HH + hh6[j]) * DHH + ee6[j]) * SS + s] = (_Float16)val;
                }
            }
    }
}

// ---------------------------------------------------------------------------
// Out-projection GEMM (unchanged from round 9): 128x64 tile, DMA +
// single-barrier dbuf, wave-tile 64x32, T2 swizzle.
// ---------------------------------------------------------------------------
__global__ __launch_bounds__(256)
void gemm_out_f16(const _Float16* __restrict__ Ah, const _Float16* __restrict__ Bt,
                  const float* __restrict__ bias, float* __restrict__ out)
{
    __shared__ _Float16 Ash[2][128][32];
    __shared__ _Float16 Bsh[2][64][32];

    const int m0 = blockIdx.x * 128;
    const int n0 = blockIdx.y * 64;
    const int tid  = threadIdx.x;
    const int wave = tid >> 6;
    const int lane = tid & 63;
    const int l16  = tid & 15;
    const int quad = (tid >> 4) & 3;
    const int wy = wave >> 1;
    const int wx = wave & 1;

    const int scol = ((lane & 3) ^ ((lane >> 3) & 3)) * 8;
    const int fcol = (quad ^ ((l16 >> 1) & 3)) * 8;

    const _Float16* ap = Ah + (size_t)(m0 + 32 * wave + (lane >> 2)) * DD + scol;
    const _Float16* bp = Bt + (size_t)(n0 + 16 * wave + (lane >> 2)) * DD + scol;

    f32x4 acc[4][2];
#pragma unroll
    for (int i = 0; i < 4; ++i)
#pragma unroll
        for (int j = 0; j < 2; ++j) acc[i][j] = (f32x4){0.f, 0.f, 0.f, 0.f};

    glds16(ap, &Ash[0][32 * wave][0]);
    glds16(ap + 16 * DD, &Ash[0][32 * wave + 16][0]);
    glds16(bp, &Bsh[0][16 * wave][0]);

    int cur = 0;
    for (int k0 = 0; k0 < DD; k0 += 32) {
        __syncthreads();
        if (k0 + 32 < DD) {
            glds16(ap + k0 + 32, &Ash[cur ^ 1][32 * wave][0]);
            glds16(ap + k0 + 32 + 16 * DD, &Ash[cur ^ 1][32 * wave + 16][0]);
            glds16(bp + k0 + 32, &Bsh[cur ^ 1][16 * wave][0]);
        }

        half8 a[4], bf[2];
#pragma unroll
        for (int i = 0; i < 4; ++i)
            a[i] = *(const half8*)&Ash[cur][wy * 64 + i * 16 + l16][fcol];
#pragma unroll
        for (int j = 0; j < 2; ++j)
            bf[j] = *(const half8*)&Bsh[cur][wx * 32 + j * 16 + l16][fcol];
#pragma unroll
        for (int i = 0; i < 4; ++i)
#pragma unroll
            for (int j = 0; j < 2; ++j)
                acc[i][j] = __builtin_amdgcn_mfma_f32_16x16x32_f16(a[i], bf[j], acc[i][j], 0, 0, 0);
        cur ^= 1;
    }

#pragma unroll
    for (int i = 0; i < 4; ++i) {
#pragma unroll
        for (int r = 0; r < 4; ++r) {
            int row = m0 + wy * 64 + i * 16 + quad * 4 + r;
#pragma unroll
            for (int j = 0; j < 2; ++j) {
                int col = n0 + wx * 32 + j * 16 + l16;
                out[(size_t)row * DD + col] = acc[i][j][r] + bias[col];
            }
        }
    }
}

// ---------------------------------------------------------------------------
// Flash attention (unchanged from round 9): f16 MFMA, 512 thr / 128 q,
// T2 swizzle on K/V^T chunk planes.
// ---------------------------------------------------------------------------
__global__ __launch_bounds__(512)
void attn_f16(const _Float16* __restrict__ qh, const _Float16* __restrict__ kh,
              const _Float16* __restrict__ vt, _Float16* __restrict__ ctxh)
{
    const int bh  = blockIdx.x;
    const int q0  = blockIdx.y * 128;
    const int tid = threadIdx.x;
    const int wave = tid >> 6;          // 0..7
    const int lane = tid & 63;
    const int l16  = tid & 15;
    const int quad = (tid >> 4) & 3;

    __shared__ _Float16 Ks[2][2][64][32];   // [dbuf][d-chunk][key][32]
    __shared__ _Float16 Vt[2][2][64][32];   // [dbuf][kk-chunk][e][32]
    __shared__ _Float16 Pt[8][16][72];      // per-wave P [q][kk]

    const int scol = ((lane & 3) ^ ((lane >> 3) & 3)) * 8;
    const int fcol = (quad ^ ((l16 >> 1) & 3)) * 8;

    // ---- Q frags: direct global (once) ----
    const _Float16* qrow = qh + ((size_t)bh * SS + q0 + wave * 16 + l16) * DHH;
    const half8 qlo = *(const half8*)(qrow + quad * 8);
    const half8 qhi = *(const half8*)(qrow + 32 + quad * 8);

    // ---- DMA sources: sub-wave sw covers 16 rows of its matrix ----
    const int sw = wave & 3;
    const _Float16* kp = kh + ((size_t)bh * SS + 16 * sw + (lane >> 2)) * DHH + scol;
    const _Float16* vp = vt + ((size_t)bh * DHH + 16 * sw + (lane >> 2)) * SS + scol;

    f32x4 o[4];
    float lacc = 0.f;
#pragma unroll
    for (int j = 0; j < 4; ++j) o[j] = (f32x4){0.f, 0.f, 0.f, 0.f};

    // ---- prefetch tile 0 -> buffer 0 ----
    if (wave < 4) {
        glds16(kp,      &Ks[0][0][16 * sw][0]);
        glds16(kp + 32, &Ks[0][1][16 * sw][0]);
    } else {
        glds16(vp,      &Vt[0][0][16 * sw][0]);
        glds16(vp + 32, &Vt[0][1][16 * sw][0]);
    }

    int cur = 0;
    for (int kt = 0; kt < SS; kt += 64) {
        __syncthreads();                 // buf[cur] ready; buf[cur^1] reads done
        if (kt + 64 < SS) {
            if (wave < 4) {
                glds16(kp + (size_t)(kt + 64) * DHH,      &Ks[cur ^ 1][0][16 * sw][0]);
                glds16(kp + (size_t)(kt + 64) * DHH + 32, &Ks[cur ^ 1][1][16 * sw][0]);
            } else {
                glds16(vp + kt + 64,      &Vt[cur ^ 1][0][16 * sw][0]);
                glds16(vp + kt + 64 + 32, &Vt[cur ^ 1][1][16 * sw][0]);
            }
        }

        // ---- S^T = K·Q^T per 16-kk tile; exp; vectorized P write ----
#pragma unroll
        for (int f = 0; f < 4; ++f) {
            half8 klo = *(const half8*)&Ks[cur][0][f * 16 + l16][fcol];
            half8 khi = *(const half8*)&Ks[cur][1][f * 16 + l16][fcol];
            f32x4 z = (f32x4){0.f, 0.f, 0.f, 0.f};
            z = __builtin_amdgcn_mfma_f32_16x16x32_f16(klo, qlo, z, 0, 0, 0);
            z = __builtin_amdgcn_mfma_f32_16x16x32_f16(khi, qhi, z, 0, 0, 0);
            half4 pk;
#pragma unroll
            for (int r = 0; r < 4; ++r) {
                float p = __expf(z[r]);
                lacc += p;
                pk[r] = (_Float16)p;
            }
            *(half4*)&Pt[wave][l16][f * 16 + quad * 4] = pk;
        }

        // ---- P A-frags (same-wave LDS round trip, in-order DS) ----
        half8 pl = *(const half8*)&Pt[wave][l16][quad * 8];
        half8 ph = *(const half8*)&Pt[wave][l16][32 + quad * 8];

        // ---- PV ----
#pragma unroll
        for (int j = 0; j < 4; ++j) {
            half8 vlo = *(const half8*)&Vt[cur][0][j * 16 + l16][fcol];
            half8 vhi = *(const half8*)&Vt[cur][1][j * 16 + l16][fcol];
            o[j] = __builtin_amdgcn_mfma_f32_16x16x32_f16(pl, vlo, o[j], 0, 0, 0);
            o[j] = __builtin_amdgcn_mfma_f32_16x16x32_f16(ph, vhi, o[j], 0, 0, 0);
        }
        cur ^= 1;
    }

    // ---- l: sum quad partials (same q = l16 across quads) ----
    float lr = lacc;
    lr += __shfl_xor(lr, 16);
    lr += __shfl_xor(lr, 32);

    const int b_ = bh / HH;
    const int h_ = bh % HH;
#pragma unroll
    for (int r = 0; r < 4; ++r) {
        float invl = 1.f / __shfl(lr, quad * 4 + r, 16);
        int s_ = q0 + wave * 16 + quad * 4 + r;
        _Float16* orow = ctxh + ((size_t)(b_ * SS + s_)) * DD + h_ * DHH;
#pragma unroll
        for (int j = 0; j < 4; ++j)
            orow[j * 16 + l16] = (_Float16)(o[j][r] * invl);
    }
}

// ---------------------------------------------------------------------------
extern "C" void kernel_launch(void* const* d_in, const int* in_sizes, int n_in,
                              void* d_out, int out_size, void* d_ws, size_t ws_size,
                              hipStream_t stream)
{
    const float* x  = (const float*)d_in[0];
    const float* Wq = (const float*)d_in[1];
    const float* bq = (const float*)d_in[2];
    const float* Wk = (const float*)d_in[3];
    const float* bk = (const float*)d_in[4];
    const float* Wv = (const float*)d_in[5];
    const float* bv = (const float*)d_in[6];
    const float* Wo = (const float*)d_in[7];
    const float* bo = (const float*)d_in[8];
    float* out = (float*)d_out;

    const size_t xe = (size_t)BSS * DD;          // 6,291,456
    const size_t we = (size_t)DD * DD;           // 589,824
    _Float16* Xh   = (_Float16*)d_ws;
    _Float16* Wt   = Xh  + xe;                   // [2304][768]
    _Float16* Wot  = Wt  + (size_t)3 * we;
    _Float16* qhb  = Wot + we;
    _Float16* khb  = qhb + xe;
    _Float16* vtb  = khb + xe;                   // [bh][e][s]
    _Float16* ctxh = vtb + xe;

    prep<<<3072 + 576, 256, 0, stream>>>(x, Xh, Wq, Wk, Wv, Wo, Wt, Wot);

    gemm_qkv_128x192<<<(BSS / 128) * (NQKV / 192), 256, 0, stream>>>(
        Xh, Wt, bq, bk, bv, qhb, khb, vtb);

    dim3 ag(BB * HH, SS / 128);      // (96, 8) = 768 blocks
    attn_f16<<<ag, 512, 0, stream>>>(qhb, khb, vtb, ctxh);

    dim3 gg(BSS / 128, DD / 64);     // (64, 12) = 768 blocks
    gemm_out_f16<<<gg, 256, 0, stream>>>(ctxh, Wot, bo, out);
}

// Round 3
// 212.182 us; speedup vs baseline: 1.0113x; 1.0113x over previous
//
#include <hip/hip_runtime.h>
#include <math.h>

#define BB 8
#define SS 1024
#define DD 768
#define HH 12
#define DHH 64
#define BSS (BB*SS)          // 8192
#define NQKV 2304            // stacked Q|K|V output columns
#define NT 24                // 768 / BK(=32) K-tiles

typedef _Float16 half8 __attribute__((ext_vector_type(8)));
typedef _Float16 half4 __attribute__((ext_vector_type(4)));
typedef float    f32x4 __attribute__((ext_vector_type(4)));

// Async global->LDS DMA, 16 B/lane. LDS dest = wave-uniform base + lane*16.
__device__ __forceinline__ void glds16(const _Float16* g, _Float16* l)
{
    __builtin_amdgcn_global_load_lds(
        (const __attribute__((address_space(1))) uint32_t*)(g),
        (__attribute__((address_space(3))) uint32_t*)(l),
        16, 0, 0);
}

// ---------------------------------------------------------------------------
// prep: one launch doing x cast (blocks 0..3071) and all 4 weight
// transposes (blocks 3072..3647).  (unchanged)
// ---------------------------------------------------------------------------
__global__ __launch_bounds__(256)
void prep(const float* __restrict__ x, _Float16* __restrict__ xh,
          const float* __restrict__ Wq, const float* __restrict__ Wk,
          const float* __restrict__ Wv, const float* __restrict__ Wo,
          _Float16* __restrict__ Wt, _Float16* __restrict__ Wot)
{
    const int blk = blockIdx.x;
    const int tid = threadIdx.x;

    if (blk < 3072) {                    // ---- cast x -> f16 ----
        int i = blk * 256 + tid;
        const float4* xp = (const float4*)x + (size_t)i * 2;
        float4 u = xp[0], v = xp[1];
        half8 h = { (_Float16)u.x, (_Float16)u.y, (_Float16)u.z, (_Float16)u.w,
                    (_Float16)v.x, (_Float16)v.y, (_Float16)v.z, (_Float16)v.w };
        ((half8*)xh)[i] = h;
        return;
    }

    // ---- weight transpose: 576 tiles = (12 d0) x (12 n) x (4 z) ----
    __shared__ float T[64][65];
    const int t  = blk - 3072;
    const int z  = t / 144;              // 0..3
    const int r_ = t - z * 144;
    const int d0 = (r_ / 12) * 64;
    const int n_outer = r_ % 12;

    const float* src;
    _Float16* dst;
    int base_mul, row_stride;
    if (z < 3) {
        src = (z == 0) ? Wq : (z == 1) ? Wk : Wv;
        dst = Wt + (size_t)z * DD * DD;
        base_mul = DD * DHH; row_stride = DHH;
    } else {
        src = Wo; dst = Wot;
        base_mul = 64; row_stride = DD;
    }

    const size_t base = (size_t)n_outer * base_mul;
    {
        int dl = tid >> 2, c0 = (tid & 3) * 16;
        const float* p = src + base + (size_t)(d0 + dl) * row_stride + c0;
#pragma unroll
        for (int m = 0; m < 4; ++m) {
            float4 f = *(const float4*)(p + m * 4);
            T[dl][c0 + m*4 + 0] = f.x;
            T[dl][c0 + m*4 + 1] = f.y;
            T[dl][c0 + m*4 + 2] = f.z;
            T[dl][c0 + m*4 + 3] = f.w;
        }
    }
    __syncthreads();
    {
        int e = tid >> 2, c = tid & 3;
        half8 lo, hi;
#pragma unroll
        for (int i = 0; i < 8; ++i) {
            lo[i] = (_Float16)T[c*16 + i][e];
            hi[i] = (_Float16)T[c*16 + 8 + i][e];
        }
        _Float16* q = dst + ((size_t)n_outer * 64 + e) * DD + d0 + c * 16;
        *(half8*)q = lo;
        *(half8*)(q + 8) = hi;
    }
}

// ---------------------------------------------------------------------------
// Stacked QKV GEMM, round-11: round-1's proven schedule (quad-buffer, stage
// kt+3 during kt, ONE counted-vmcnt gate + s_barrier per K-tile, setprio,
// T2 swizzle) with fixed geometry: 256x288 tile -> 32 x 8 = 256 blocks =
// EXACTLY 1 block/CU, zero dispatch tail.  8 waves, wave-tile 64x144
// (acc[4][9]).  LDS: A[4][256][32] + B[4][288][32] = 136 KB.
// Staging per tile: every wave 2 A-chunks + 2 B-chunks; waves 0,4 one extra
// B-chunk (rows 256-271 / 272-287) -> per-wave gate constants 10/5/0 vs
// 8/4/0 (wave-uniform waitcnt branch, shared s_barrier).
// Epilogue: Q|K|V boundary resolved per 16-col fragment (768 is 16-aligned).
// ---------------------------------------------------------------------------
#define WAITV(N) asm volatile("s_waitcnt vmcnt(" #N ")" ::: "memory")

__global__ __launch_bounds__(512, 2)
void gemm_qkv_256x288(const _Float16* __restrict__ Xh, const _Float16* __restrict__ Wt,
                      const float* __restrict__ bq, const float* __restrict__ bk,
                      const float* __restrict__ bv,
                      _Float16* __restrict__ qo, _Float16* __restrict__ ko,
                      _Float16* __restrict__ vto)
{
    __shared__ _Float16 Ab[4][256][32];   // 64 KB
    __shared__ _Float16 Bb[4][288][32];   // 72 KB

    const int bid = blockIdx.x;          // 0..255
    const int c8  = bid & 7;             // XCD
    const int g   = bid >> 3;            // 0..31
    const int m_t = c8 * 4 + (g >> 3);   // 0..31
    const int n_t = g & 7;               // 0..7
    const int m0 = m_t * 256;
    const int n0 = n_t * 288;

    const int tid  = threadIdx.x;
    const int wave = tid >> 6;           // 0..7
    const int lane = tid & 63;
    const int l16  = tid & 15;
    const int quad = (tid >> 4) & 3;
    const int wy = wave >> 1;            // 0..3 : wave tile 64x144
    const int wx = wave & 1;             // 0..1

    // T2 swizzle: inverse involution on the global source column so the
    // linear DMA lands data at swizzled LDS slots; reads use the same XOR.
    const int scol = ((lane & 3) ^ ((lane >> 3) & 3)) * 8;
    const int fcol = (quad ^ ((l16 >> 1) & 3)) * 8;

    const bool big = (wave == 0) || (wave == 4);   // 5 loads/tile vs 4

    // staging sources: wave stages A rows [32w,32w+32), B rows [32w,32w+32),
    // waves 0/4 additionally B rows 256-271 / 272-287.
    const _Float16* apA = Xh + (size_t)(m0 + 32 * wave + (lane >> 2)) * DD + scol;
    const _Float16* bpB = Wt + (size_t)(n0 + 32 * wave + (lane >> 2)) * DD + scol;
    const _Float16* bpX = Wt + (size_t)(n0 + 256 + ((wave & 4) << 2) + (lane >> 2)) * DD + scol;
    const int xrow = 256 + ((wave & 4) << 2);

#define STAGE(buf, kt) do {                                               \
        glds16(apA + (kt) * 32,           &Ab[buf][32 * wave][0]);        \
        glds16(apA + (kt) * 32 + 16 * DD, &Ab[buf][32 * wave + 16][0]);   \
        glds16(bpB + (kt) * 32,           &Bb[buf][32 * wave][0]);        \
        glds16(bpB + (kt) * 32 + 16 * DD, &Bb[buf][32 * wave + 16][0]);   \
        if (big) glds16(bpX + (kt) * 32,  &Bb[buf][xrow][0]);             \
    } while (0)

    f32x4 acc[4][9];
#pragma unroll
    for (int i = 0; i < 4; ++i)
#pragma unroll
        for (int j = 0; j < 9; ++j) acc[i][j] = (f32x4){0.f, 0.f, 0.f, 0.f};

    // ---- prologue: stage tiles 0,1,2 ----
    STAGE(0, 0); STAGE(1, 1); STAGE(2, 2);
    if (big) WAITV(10); else WAITV(8);   // tile 0 resident
    __builtin_amdgcn_s_barrier();

    for (int kt = 0; kt < NT; ++kt) {
        const int buf = kt & 3;

        // ---- frag reads (13 x ds_read_b128) ----
        half8 a[4], bf[9];
#pragma unroll
        for (int i = 0; i < 4; ++i)
            a[i] = *(const half8*)&Ab[buf][wy * 64 + i * 16 + l16][fcol];
#pragma unroll
        for (int j = 0; j < 9; ++j)
            bf[j] = *(const half8*)&Bb[buf][wx * 144 + j * 16 + l16][fcol];

        // ---- stage tile kt+3 (into buf (kt-1)&3, read-retired last iter) ----
        if (kt < NT - 3) {
            const int nb = (kt + 3) & 3;
            STAGE(nb, kt + 3);
        }

        // ---- MFMA cluster ----
        __builtin_amdgcn_s_setprio(1);
#pragma unroll
        for (int i = 0; i < 4; ++i)
#pragma unroll
            for (int j = 0; j < 9; ++j)
                acc[i][j] = __builtin_amdgcn_mfma_f32_16x16x32_f16(a[i], bf[j], acc[i][j], 0, 0, 0);
        __builtin_amdgcn_s_setprio(0);

        // ---- gate: tile kt+1 must be resident before next iter ----
        if (kt < NT - 3) {
            if (big) WAITV(10); else WAITV(8);
            __builtin_amdgcn_s_barrier();
        } else if (kt == NT - 3) {
            if (big) WAITV(5); else WAITV(4);
            __builtin_amdgcn_s_barrier();
        } else if (kt == NT - 2) {
            WAITV(0);
            __builtin_amdgcn_s_barrier();
        }
    }
#undef STAGE

    // ---- epilogue: per-fragment Q|K|V resolution (boundaries 16-aligned) ----
    float bvv[9]; int hh9[9], ee9[9], ws9[9];
#pragma unroll
    for (int j = 0; j < 9; ++j) {
        int nl = n0 + wx * 144 + j * 16 + l16;   // 0..2303
        int ws = nl / 768;                        // 0=Q 1=K 2=V (frag-uniform)
        int nloc = nl - ws * 768;
        const float* bp_ = (ws == 0) ? bq : (ws == 1) ? bk : bv;
        bvv[j] = bp_[nloc];
        hh9[j] = nloc >> 6;
        ee9[j] = nloc & 63;
        ws9[j] = ws;
    }

#pragma unroll
    for (int i = 0; i < 4; ++i) {
#pragma unroll
        for (int r = 0; r < 4; ++r) {
            int row = m0 + wy * 64 + i * 16 + quad * 4 + r;
            int b_ = row >> 10;
            int s  = row & (SS - 1);
#pragma unroll
            for (int j = 0; j < 9; ++j) {
                float val = acc[i][j][r] + bvv[j];
                if (ws9[j] == 0)
                    qo[((size_t)(b_ * HH + hh9[j]) * SS + s) * DHH + ee9[j]] = (_Float16)(val * 0.125f);
                else if (ws9[j] == 1)
                    ko[((size_t)(b_ * HH + hh9[j]) * SS + s) * DHH + ee9[j]] = (_Float16)val;
                else
                    vto[((size_t)(b_ * HH + hh9[j]) * DHH + ee9[j]) * SS + s] = (_Float16)val;
            }
        }
    }
}

// ---------------------------------------------------------------------------
// Out-projection GEMM (unchanged): 128x64 tile, DMA + single-barrier dbuf,
// wave-tile 64x32, T2 swizzle.
// ---------------------------------------------------------------------------
__global__ __launch_bounds__(256)
void gemm_out_f16(const _Float16* __restrict__ Ah, const _Float16* __restrict__ Bt,
                  const float* __restrict__ bias, float* __restrict__ out)
{
    __shared__ _Float16 Ash[2][128][32];
    __shared__ _Float16 Bsh[2][64][32];

    const int m0 = blockIdx.x * 128;
    const int n0 = blockIdx.y * 64;
    const int tid  = threadIdx.x;
    const int wave = tid >> 6;
    const int lane = tid & 63;
    const int l16  = tid & 15;
    const int quad = (tid >> 4) & 3;
    const int wy = wave >> 1;
    const int wx = wave & 1;

    const int scol = ((lane & 3) ^ ((lane >> 3) & 3)) * 8;
    const int fcol = (quad ^ ((l16 >> 1) & 3)) * 8;

    const _Float16* ap = Ah + (size_t)(m0 + 32 * wave + (lane >> 2)) * DD + scol;
    const _Float16* bp = Bt + (size_t)(n0 + 16 * wave + (lane >> 2)) * DD + scol;

    f32x4 acc[4][2];
#pragma unroll
    for (int i = 0; i < 4; ++i)
#pragma unroll
        for (int j = 0; j < 2; ++j) acc[i][j] = (f32x4){0.f, 0.f, 0.f, 0.f};

    glds16(ap, &Ash[0][32 * wave][0]);
    glds16(ap + 16 * DD, &Ash[0][32 * wave + 16][0]);
    glds16(bp, &Bsh[0][16 * wave][0]);

    int cur = 0;
    for (int k0 = 0; k0 < DD; k0 += 32) {
        __syncthreads();
        if (k0 + 32 < DD) {
            glds16(ap + k0 + 32, &Ash[cur ^ 1][32 * wave][0]);
            glds16(ap + k0 + 32 + 16 * DD, &Ash[cur ^ 1][32 * wave + 16][0]);
            glds16(bp + k0 + 32, &Bsh[cur ^ 1][16 * wave][0]);
        }

        half8 a[4], bf[2];
#pragma unroll
        for (int i = 0; i < 4; ++i)
            a[i] = *(const half8*)&Ash[cur][wy * 64 + i * 16 + l16][fcol];
#pragma unroll
        for (int j = 0; j < 2; ++j)
            bf[j] = *(const half8*)&Bsh[cur][wx * 32 + j * 16 + l16][fcol];
#pragma unroll
        for (int i = 0; i < 4; ++i)
#pragma unroll
            for (int j = 0; j < 2; ++j)
                acc[i][j] = __builtin_amdgcn_mfma_f32_16x16x32_f16(a[i], bf[j], acc[i][j], 0, 0, 0);
        cur ^= 1;
    }

#pragma unroll
    for (int i = 0; i < 4; ++i) {
#pragma unroll
        for (int r = 0; r < 4; ++r) {
            int row = m0 + wy * 64 + i * 16 + quad * 4 + r;
#pragma unroll
            for (int j = 0; j < 2; ++j) {
                int col = n0 + wx * 32 + j * 16 + l16;
                out[(size_t)row * DD + col] = acc[i][j][r] + bias[col];
            }
        }
    }
}

// ---------------------------------------------------------------------------
// Flash attention (unchanged): f16 MFMA, 512 thr / 128 q, T2 swizzle on
// K/V^T chunk planes.
// ---------------------------------------------------------------------------
__global__ __launch_bounds__(512)
void attn_f16(const _Float16* __restrict__ qh, const _Float16* __restrict__ kh,
              const _Float16* __restrict__ vt, _Float16* __restrict__ ctxh)
{
    const int bh  = blockIdx.x;
    const int q0  = blockIdx.y * 128;
    const int tid = threadIdx.x;
    const int wave = tid >> 6;          // 0..7
    const int lane = tid & 63;
    const int l16  = tid & 15;
    const int quad = (tid >> 4) & 3;

    __shared__ _Float16 Ks[2][2][64][32];   // [dbuf][d-chunk][key][32]
    __shared__ _Float16 Vt[2][2][64][32];   // [dbuf][kk-chunk][e][32]
    __shared__ _Float16 Pt[8][16][72];      // per-wave P [q][kk]

    const int scol = ((lane & 3) ^ ((lane >> 3) & 3)) * 8;
    const int fcol = (quad ^ ((l16 >> 1) & 3)) * 8;

    // ---- Q frags: direct global (once) ----
    const _Float16* qrow = qh + ((size_t)bh * SS + q0 + wave * 16 + l16) * DHH;
    const half8 qlo = *(const half8*)(qrow + quad * 8);
    const half8 qhi = *(const half8*)(qrow + 32 + quad * 8);

    // ---- DMA sources: sub-wave sw covers 16 rows of its matrix ----
    const int sw = wave & 3;
    const _Float16* kp = kh + ((size_t)bh * SS + 16 * sw + (lane >> 2)) * DHH + scol;
    const _Float16* vp = vt + ((size_t)bh * DHH + 16 * sw + (lane >> 2)) * SS + scol;

    f32x4 o[4];
    float lacc = 0.f;
#pragma unroll
    for (int j = 0; j < 4; ++j) o[j] = (f32x4){0.f, 0.f, 0.f, 0.f};

    // ---- prefetch tile 0 -> buffer 0 ----
    if (wave < 4) {
        glds16(kp,      &Ks[0][0][16 * sw][0]);
        glds16(kp + 32, &Ks[0][1][16 * sw][0]);
    } else {
        glds16(vp,      &Vt[0][0][16 * sw][0]);
        glds16(vp + 32, &Vt[0][1][16 * sw][0]);
    }

    int cur = 0;
    for (int kt = 0; kt < SS; kt += 64) {
        __syncthreads();                 // buf[cur] ready; buf[cur^1] reads done
        if (kt + 64 < SS) {
            if (wave < 4) {
                glds16(kp + (size_t)(kt + 64) * DHH,      &Ks[cur ^ 1][0][16 * sw][0]);
                glds16(kp + (size_t)(kt + 64) * DHH + 32, &Ks[cur ^ 1][1][16 * sw][0]);
            } else {
                glds16(vp + kt + 64,      &Vt[cur ^ 1][0][16 * sw][0]);
                glds16(vp + kt + 64 + 32, &Vt[cur ^ 1][1][16 * sw][0]);
            }
        }

        // ---- S^T = K·Q^T per 16-kk tile; exp; vectorized P write ----
#pragma unroll
        for (int f = 0; f < 4; ++f) {
            half8 klo = *(const half8*)&Ks[cur][0][f * 16 + l16][fcol];
            half8 khi = *(const half8*)&Ks[cur][1][f * 16 + l16][fcol];
            f32x4 z = (f32x4){0.f, 0.f, 0.f, 0.f};
            z = __builtin_amdgcn_mfma_f32_16x16x32_f16(klo, qlo, z, 0, 0, 0);
            z = __builtin_amdgcn_mfma_f32_16x16x32_f16(khi, qhi, z, 0, 0, 0);
            half4 pk;
#pragma unroll
            for (int r = 0; r < 4; ++r) {
                float p = __expf(z[r]);
                lacc += p;
                pk[r] = (_Float16)p;
            }
            *(half4*)&Pt[wave][l16][f * 16 + quad * 4] = pk;
        }

        // ---- P A-frags (same-wave LDS round trip, in-order DS) ----
        half8 pl = *(const half8*)&Pt[wave][l16][quad * 8];
        half8 ph = *(const half8*)&Pt[wave][l16][32 + quad * 8];

        // ---- PV ----
#pragma unroll
        for (int j = 0; j < 4; ++j) {
            half8 vlo = *(const half8*)&Vt[cur][0][j * 16 + l16][fcol];
            half8 vhi = *(const half8*)&Vt[cur][1][j * 16 + l16][fcol];
            o[j] = __builtin_amdgcn_mfma_f32_16x16x32_f16(pl, vlo, o[j], 0, 0, 0);
            o[j] = __builtin_amdgcn_mfma_f32_16x16x32_f16(ph, vhi, o[j], 0, 0, 0);
        }
        cur ^= 1;
    }

    // ---- l: sum quad partials (same q = l16 across quads) ----
    float lr = lacc;
    lr += __shfl_xor(lr, 16);
    lr += __shfl_xor(lr, 32);

    const int b_ = bh / HH;
    const int h_ = bh % HH;
#pragma unroll
    for (int r = 0; r < 4; ++r) {
        float invl = 1.f / __shfl(lr, quad * 4 + r, 16);
        int s_ = q0 + wave * 16 + quad * 4 + r;
        _Float16* orow = ctxh + ((size_t)(b_ * SS + s_)) * DD + h_ * DHH;
#pragma unroll
        for (int j = 0; j < 4; ++j)
            orow[j * 16 + l16] = (_Float16)(o[j][r] * invl);
    }
}

// ---------------------------------------------------------------------------
extern "C" void kernel_launch(void* const* d_in, const int* in_sizes, int n_in,
                              void* d_out, int out_size, void* d_ws, size_t ws_size,
                              hipStream_t stream)
{
    const float* x  = (const float*)d_in[0];
    const float* Wq = (const float*)d_in[1];
    const float* bq = (const float*)d_in[2];
    const float* Wk = (const float*)d_in[3];
    const float* bk = (const float*)d_in[4];
    const float* Wv = (const float*)d_in[5];
    const float* bv = (const float*)d_in[6];
    const float* Wo = (const float*)d_in[7];
    const float* bo = (const float*)d_in[8];
    float* out = (float*)d_out;

    const size_t xe = (size_t)BSS * DD;          // 6,291,456
    const size_t we = (size_t)DD * DD;           // 589,824
    _Float16* Xh   = (_Float16*)d_ws;
    _Float16* Wt   = Xh  + xe;                   // [2304][768]
    _Float16* Wot  = Wt  + (size_t)3 * we;
    _Float16* qhb  = Wot + we;
    _Float16* khb  = qhb + xe;
    _Float16* vtb  = khb + xe;                   // [bh][e][s]
    _Float16* ctxh = vtb + xe;

    prep<<<3072 + 576, 256, 0, stream>>>(x, Xh, Wq, Wk, Wv, Wo, Wt, Wot);

    gemm_qkv_256x288<<<(BSS / 256) * (NQKV / 288), 512, 0, stream>>>(
        Xh, Wt, bq, bk, bv, qhb, khb, vtb);

    dim3 ag(BB * HH, SS / 128);      // (96, 8) = 768 blocks
    attn_f16<<<ag, 512, 0, stream>>>(qhb, khb, vtb, ctxh);

    dim3 gg(BSS / 128, DD / 64);     // (64, 12) = 768 blocks
    gemm_out_f16<<<gg, 256, 0, stream>>>(ctxh, Wot, bo, out);
}

// Round 4
// 207.156 us; speedup vs baseline: 1.0359x; 1.0243x over previous
//
#include <hip/hip_runtime.h>
#include <math.h>

#define BB 8
#define SS 1024
#define DD 768
#define HH 12
#define DHH 64
#define BSS (BB*SS)          // 8192
#define NQKV 2304            // stacked Q|K|V output columns
#define NT 24                // 768 / BK(=32) K-tiles

typedef _Float16 half8 __attribute__((ext_vector_type(8)));
typedef _Float16 half4 __attribute__((ext_vector_type(4)));
typedef float    f32x4 __attribute__((ext_vector_type(4)));

// Async global->LDS DMA, 16 B/lane. LDS dest = wave-uniform base + lane*16.
__device__ __forceinline__ void glds16(const _Float16* g, _Float16* l)
{
    __builtin_amdgcn_global_load_lds(
        (const __attribute__((address_space(1))) uint32_t*)(g),
        (__attribute__((address_space(3))) uint32_t*)(l),
        16, 0, 0);
}

#define WAITV(N) asm volatile("s_waitcnt vmcnt(" #N ")" ::: "memory")

// ---------------------------------------------------------------------------
// prep: one launch doing x cast (blocks 0..3071) and all 4 weight
// transposes (blocks 3072..3647).  (unchanged)
// ---------------------------------------------------------------------------
__global__ __launch_bounds__(256)
void prep(const float* __restrict__ x, _Float16* __restrict__ xh,
          const float* __restrict__ Wq, const float* __restrict__ Wk,
          const float* __restrict__ Wv, const float* __restrict__ Wo,
          _Float16* __restrict__ Wt, _Float16* __restrict__ Wot)
{
    const int blk = blockIdx.x;
    const int tid = threadIdx.x;

    if (blk < 3072) {                    // ---- cast x -> f16 ----
        int i = blk * 256 + tid;
        const float4* xp = (const float4*)x + (size_t)i * 2;
        float4 u = xp[0], v = xp[1];
        half8 h = { (_Float16)u.x, (_Float16)u.y, (_Float16)u.z, (_Float16)u.w,
                    (_Float16)v.x, (_Float16)v.y, (_Float16)v.z, (_Float16)v.w };
        ((half8*)xh)[i] = h;
        return;
    }

    // ---- weight transpose: 576 tiles = (12 d0) x (12 n) x (4 z) ----
    __shared__ float T[64][65];
    const int t  = blk - 3072;
    const int z  = t / 144;              // 0..3
    const int r_ = t - z * 144;
    const int d0 = (r_ / 12) * 64;
    const int n_outer = r_ % 12;

    const float* src;
    _Float16* dst;
    int base_mul, row_stride;
    if (z < 3) {
        src = (z == 0) ? Wq : (z == 1) ? Wk : Wv;
        dst = Wt + (size_t)z * DD * DD;
        base_mul = DD * DHH; row_stride = DHH;
    } else {
        src = Wo; dst = Wot;
        base_mul = 64; row_stride = DD;
    }

    const size_t base = (size_t)n_outer * base_mul;
    {
        int dl = tid >> 2, c0 = (tid & 3) * 16;
        const float* p = src + base + (size_t)(d0 + dl) * row_stride + c0;
#pragma unroll
        for (int m = 0; m < 4; ++m) {
            float4 f = *(const float4*)(p + m * 4);
            T[dl][c0 + m*4 + 0] = f.x;
            T[dl][c0 + m*4 + 1] = f.y;
            T[dl][c0 + m*4 + 2] = f.z;
            T[dl][c0 + m*4 + 3] = f.w;
        }
    }
    __syncthreads();
    {
        int e = tid >> 2, c = tid & 3;
        half8 lo, hi;
#pragma unroll
        for (int i = 0; i < 8; ++i) {
            lo[i] = (_Float16)T[c*16 + i][e];
            hi[i] = (_Float16)T[c*16 + 8 + i][e];
        }
        _Float16* q = dst + ((size_t)n_outer * 64 + e) * DD + d0 + c * 16;
        *(half8*)q = lo;
        *(half8*)(q + 8) = hi;
    }
}

// ---------------------------------------------------------------------------
// Stacked QKV GEMM, round-12: 256x128 tile, 4 waves (wave-tile 128x64 =
// round-1's proven acc[8][4] schedule), TRIPLE-buffered LDS (73.7 KB ->
// 2 blocks/CU co-resident for cross-block stall hiding), counted vmcnt(6)
// gate (never drains until tail), T2 swizzle, T5 setprio.  Grid 32x18 =
// 576 blocks (small-block tail amortization, ~+12% makespan only).
// Per XCD: B panel 2304x768 f16 = 3.5 MB -> L2-resident.
// ---------------------------------------------------------------------------
__global__ __launch_bounds__(256, 2)
void gemm_qkv_256x128(const _Float16* __restrict__ Xh, const _Float16* __restrict__ Wt,
                      const float* __restrict__ bq, const float* __restrict__ bk,
                      const float* __restrict__ bv,
                      _Float16* __restrict__ qo, _Float16* __restrict__ ko,
                      _Float16* __restrict__ vto)
{
    __shared__ _Float16 Ab[3][256][32];   // 48 KB
    __shared__ _Float16 Bb[3][128][32];   // 24 KB

    const int bid = blockIdx.x;          // 0..575
    const int c8  = bid & 7;             // XCD (576 % 8 == 0, bijective)
    const int g   = bid >> 3;            // 0..71
    const int m_t = c8 * 4 + g / 18;     // 0..31
    const int n_t = g % 18;              // 0..17
    const int m0 = m_t * 256;
    const int n0 = n_t * 128;

    const int tid  = threadIdx.x;
    const int wave = tid >> 6;           // 0..3
    const int lane = tid & 63;
    const int l16  = tid & 15;
    const int quad = (tid >> 4) & 3;
    const int wy = wave >> 1;            // 0..1 : wave tile 128x64
    const int wx = wave & 1;             // 0..1

    // T2 swizzle: inverse involution on the global source column so the
    // linear DMA lands data at swizzled LDS slots; reads use the same XOR.
    const int scol = ((lane & 3) ^ ((lane >> 3) & 3)) * 8;
    const int fcol = (quad ^ ((l16 >> 1) & 3)) * 8;

    // staging: wave covers A rows [64w, 64w+64) (4 chunks), B rows
    // [32w, 32w+32) (2 chunks) -> 6 glds16/wave/tile.
    const _Float16* apA = Xh + (size_t)(m0 + 64 * wave + (lane >> 2)) * DD + scol;
    const _Float16* bpB = Wt + (size_t)(n0 + 32 * wave + (lane >> 2)) * DD + scol;

#define STAGE(buf, kt) do {                                               \
        glds16(apA + (kt) * 32,           &Ab[buf][64 * wave][0]);        \
        glds16(apA + (kt) * 32 + 16 * DD, &Ab[buf][64 * wave + 16][0]);   \
        glds16(apA + (kt) * 32 + 32 * DD, &Ab[buf][64 * wave + 32][0]);   \
        glds16(apA + (kt) * 32 + 48 * DD, &Ab[buf][64 * wave + 48][0]);   \
        glds16(bpB + (kt) * 32,           &Bb[buf][32 * wave][0]);        \
        glds16(bpB + (kt) * 32 + 16 * DD, &Bb[buf][32 * wave + 16][0]);   \
    } while (0)

    f32x4 acc[8][4];
#pragma unroll
    for (int i = 0; i < 8; ++i)
#pragma unroll
        for (int j = 0; j < 4; ++j) acc[i][j] = (f32x4){0.f, 0.f, 0.f, 0.f};

#define QCOMPUTE(buf)                                                       \
    {                                                                       \
        half8 a[8], bf[4];                                                  \
        _Pragma("unroll")                                                   \
        for (int i = 0; i < 8; ++i)                                         \
            a[i] = *(const half8*)&Ab[buf][wy * 128 + i * 16 + l16][fcol];  \
        _Pragma("unroll")                                                   \
        for (int j = 0; j < 4; ++j)                                         \
            bf[j] = *(const half8*)&Bb[buf][wx * 64 + j * 16 + l16][fcol];  \
        __builtin_amdgcn_s_setprio(1);                                      \
        _Pragma("unroll")                                                   \
        for (int i = 0; i < 8; ++i)                                         \
            _Pragma("unroll")                                               \
            for (int j = 0; j < 4; ++j)                                     \
                acc[i][j] = __builtin_amdgcn_mfma_f32_16x16x32_f16(a[i], bf[j], acc[i][j], 0, 0, 0); \
        __builtin_amdgcn_s_setprio(0);                                      \
    }

    // ---- prologue: stage tiles 0,1 ----
    STAGE(0, 0); STAGE(1, 1);
    WAITV(6);                            // tile 0 resident (per-wave 6 loads)
    __builtin_amdgcn_s_barrier();

    int cur = 0;
    for (int kt = 0; kt < NT - 2; ++kt) {           // 0..21
        const int stg = cur ? cur - 1 : 2;          // (cur+2)%3
        STAGE(stg, kt + 2);                         // issue DMA first
        QCOMPUTE(cur);
        WAITV(6);                                   // tile kt+1 resident
        __builtin_amdgcn_s_barrier();
        cur = (cur == 2) ? 0 : cur + 1;
    }
    // kt=22 (buf 1): no stage; tile 23's 6 loads outstanding
    QCOMPUTE(1);
    WAITV(0);
    __builtin_amdgcn_s_barrier();
    // kt=23 (buf 2)
    QCOMPUTE(2);

#undef QCOMPUTE
#undef STAGE

    // ---- epilogue: n-tile (128 cols) entirely within Q, K, or V ----
    const int wsel = n0 / 768;           // 0=Q, 1=K, 2=V (768 % 128 == 0)
    const int nb = n0 - wsel * 768 + wx * 64;
    const float* bp_ = (wsel == 0) ? bq : (wsel == 1) ? bk : bv;

    float bvv[4]; int hh4[4], ee4[4];
#pragma unroll
    for (int j = 0; j < 4; ++j) {
        int nl = nb + j * 16 + l16;      // h*64 + e
        bvv[j] = bp_[nl];
        hh4[j] = nl >> 6;
        ee4[j] = nl & 63;
    }

    if (wsel == 0) {
#pragma unroll
        for (int i = 0; i < 8; ++i)
#pragma unroll
            for (int r = 0; r < 4; ++r) {
                int row = m0 + wy * 128 + i * 16 + quad * 4 + r;
                int b_ = row >> 10;
                int s  = row & (SS - 1);
#pragma unroll
                for (int j = 0; j < 4; ++j) {
                    float val = (acc[i][j][r] + bvv[j]) * 0.125f;
                    qo[((size_t)(b_ * HH + hh4[j]) * SS + s) * DHH + ee4[j]] = (_Float16)val;
                }
            }
    } else if (wsel == 1) {
#pragma unroll
        for (int i = 0; i < 8; ++i)
#pragma unroll
            for (int r = 0; r < 4; ++r) {
                int row = m0 + wy * 128 + i * 16 + quad * 4 + r;
                int b_ = row >> 10;
                int s  = row & (SS - 1);
#pragma unroll
                for (int j = 0; j < 4; ++j) {
                    float val = acc[i][j][r] + bvv[j];
                    ko[((size_t)(b_ * HH + hh4[j]) * SS + s) * DHH + ee4[j]] = (_Float16)val;
                }
            }
    } else {
#pragma unroll
        for (int i = 0; i < 8; ++i)
#pragma unroll
            for (int r = 0; r < 4; ++r) {
                int row = m0 + wy * 128 + i * 16 + quad * 4 + r;
                int b_ = row >> 10;
                int s  = row & (SS - 1);
#pragma unroll
                for (int j = 0; j < 4; ++j) {
                    float val = acc[i][j][r] + bvv[j];
                    vto[((size_t)(b_ * HH + hh4[j]) * DHH + ee4[j]) * SS + s] = (_Float16)val;
                }
            }
    }
}

// ---------------------------------------------------------------------------
// Out-projection GEMM, round-12: 128x64 tile, TRIPLE-buffered (36.9 KB, all
// 768 blocks still co-resident) + counted vmcnt(3) gate.  Wave-tile 64x32,
// T2 swizzle.
// ---------------------------------------------------------------------------
__global__ __launch_bounds__(256)
void gemm_out_f16(const _Float16* __restrict__ Ah, const _Float16* __restrict__ Bt,
                  const float* __restrict__ bias, float* __restrict__ out)
{
    __shared__ _Float16 Ash[3][128][32];
    __shared__ _Float16 Bsh[3][64][32];

    const int m0 = blockIdx.x * 128;
    const int n0 = blockIdx.y * 64;
    const int tid  = threadIdx.x;
    const int wave = tid >> 6;
    const int lane = tid & 63;
    const int l16  = tid & 15;
    const int quad = (tid >> 4) & 3;
    const int wy = wave >> 1;
    const int wx = wave & 1;

    const int scol = ((lane & 3) ^ ((lane >> 3) & 3)) * 8;
    const int fcol = (quad ^ ((l16 >> 1) & 3)) * 8;

    const _Float16* ap = Ah + (size_t)(m0 + 32 * wave + (lane >> 2)) * DD + scol;
    const _Float16* bp = Bt + (size_t)(n0 + 16 * wave + (lane >> 2)) * DD + scol;

#define OSTAGE(buf, kt) do {                                              \
        glds16(ap + (kt) * 32,           &Ash[buf][32 * wave][0]);        \
        glds16(ap + (kt) * 32 + 16 * DD, &Ash[buf][32 * wave + 16][0]);   \
        glds16(bp + (kt) * 32,           &Bsh[buf][16 * wave][0]);        \
    } while (0)

    f32x4 acc[4][2];
#pragma unroll
    for (int i = 0; i < 4; ++i)
#pragma unroll
        for (int j = 0; j < 2; ++j) acc[i][j] = (f32x4){0.f, 0.f, 0.f, 0.f};

#define OCOMPUTE(buf)                                                       \
    {                                                                       \
        half8 a[4], bf[2];                                                  \
        _Pragma("unroll")                                                   \
        for (int i = 0; i < 4; ++i)                                         \
            a[i] = *(const half8*)&Ash[buf][wy * 64 + i * 16 + l16][fcol];  \
        _Pragma("unroll")                                                   \
        for (int j = 0; j < 2; ++j)                                         \
            bf[j] = *(const half8*)&Bsh[buf][wx * 32 + j * 16 + l16][fcol]; \
        __builtin_amdgcn_s_setprio(1);                                      \
        _Pragma("unroll")                                                   \
        for (int i = 0; i < 4; ++i)                                         \
            _Pragma("unroll")                                               \
            for (int j = 0; j < 2; ++j)                                     \
                acc[i][j] = __builtin_amdgcn_mfma_f32_16x16x32_f16(a[i], bf[j], acc[i][j], 0, 0, 0); \
        __builtin_amdgcn_s_setprio(0);                                      \
    }

    OSTAGE(0, 0); OSTAGE(1, 1);
    WAITV(3);
    __builtin_amdgcn_s_barrier();

    int cur = 0;
    for (int kt = 0; kt < NT - 2; ++kt) {           // 0..21
        const int stg = cur ? cur - 1 : 2;
        OSTAGE(stg, kt + 2);
        OCOMPUTE(cur);
        WAITV(3);
        __builtin_amdgcn_s_barrier();
        cur = (cur == 2) ? 0 : cur + 1;
    }
    OCOMPUTE(1);
    WAITV(0);
    __builtin_amdgcn_s_barrier();
    OCOMPUTE(2);

#undef OCOMPUTE
#undef OSTAGE

#pragma unroll
    for (int i = 0; i < 4; ++i) {
#pragma unroll
        for (int r = 0; r < 4; ++r) {
            int row = m0 + wy * 64 + i * 16 + quad * 4 + r;
#pragma unroll
            for (int j = 0; j < 2; ++j) {
                int col = n0 + wx * 32 + j * 16 + l16;
                out[(size_t)row * DD + col] = acc[i][j][r] + bias[col];
            }
        }
    }
}

// ---------------------------------------------------------------------------
// Flash attention (unchanged: double-buffer keeps 50 KB LDS -> 3 blocks/CU,
// all 768 blocks co-resident; triple-buffering would break residency).
// ---------------------------------------------------------------------------
__global__ __launch_bounds__(512)
void attn_f16(const _Float16* __restrict__ qh, const _Float16* __restrict__ kh,
              const _Float16* __restrict__ vt, _Float16* __restrict__ ctxh)
{
    const int bh  = blockIdx.x;
    const int q0  = blockIdx.y * 128;
    const int tid = threadIdx.x;
    const int wave = tid >> 6;          // 0..7
    const int lane = tid & 63;
    const int l16  = tid & 15;
    const int quad = (tid >> 4) & 3;

    __shared__ _Float16 Ks[2][2][64][32];   // [dbuf][d-chunk][key][32]
    __shared__ _Float16 Vt[2][2][64][32];   // [dbuf][kk-chunk][e][32]
    __shared__ _Float16 Pt[8][16][72];      // per-wave P [q][kk]

    const int scol = ((lane & 3) ^ ((lane >> 3) & 3)) * 8;
    const int fcol = (quad ^ ((l16 >> 1) & 3)) * 8;

    // ---- Q frags: direct global (once) ----
    const _Float16* qrow = qh + ((size_t)bh * SS + q0 + wave * 16 + l16) * DHH;
    const half8 qlo = *(const half8*)(qrow + quad * 8);
    const half8 qhi = *(const half8*)(qrow + 32 + quad * 8);

    // ---- DMA sources: sub-wave sw covers 16 rows of its matrix ----
    const int sw = wave & 3;
    const _Float16* kp = kh + ((size_t)bh * SS + 16 * sw + (lane >> 2)) * DHH + scol;
    const _Float16* vp = vt + ((size_t)bh * DHH + 16 * sw + (lane >> 2)) * SS + scol;

    f32x4 o[4];
    float lacc = 0.f;
#pragma unroll
    for (int j = 0; j < 4; ++j) o[j] = (f32x4){0.f, 0.f, 0.f, 0.f};

    // ---- prefetch tile 0 -> buffer 0 ----
    if (wave < 4) {
        glds16(kp,      &Ks[0][0][16 * sw][0]);
        glds16(kp + 32, &Ks[0][1][16 * sw][0]);
    } else {
        glds16(vp,      &Vt[0][0][16 * sw][0]);
        glds16(vp + 32, &Vt[0][1][16 * sw][0]);
    }

    int cur = 0;
    for (int kt = 0; kt < SS; kt += 64) {
        __syncthreads();                 // buf[cur] ready; buf[cur^1] reads done
        if (kt + 64 < SS) {
            if (wave < 4) {
                glds16(kp + (size_t)(kt + 64) * DHH,      &Ks[cur ^ 1][0][16 * sw][0]);
                glds16(kp + (size_t)(kt + 64) * DHH + 32, &Ks[cur ^ 1][1][16 * sw][0]);
            } else {
                glds16(vp + kt + 64,      &Vt[cur ^ 1][0][16 * sw][0]);
                glds16(vp + kt + 64 + 32, &Vt[cur ^ 1][1][16 * sw][0]);
            }
        }

        // ---- S^T = K·Q^T per 16-kk tile; exp; vectorized P write ----
#pragma unroll
        for (int f = 0; f < 4; ++f) {
            half8 klo = *(const half8*)&Ks[cur][0][f * 16 + l16][fcol];
            half8 khi = *(const half8*)&Ks[cur][1][f * 16 + l16][fcol];
            f32x4 z = (f32x4){0.f, 0.f, 0.f, 0.f};
            z = __builtin_amdgcn_mfma_f32_16x16x32_f16(klo, qlo, z, 0, 0, 0);
            z = __builtin_amdgcn_mfma_f32_16x16x32_f16(khi, qhi, z, 0, 0, 0);
            half4 pk;
#pragma unroll
            for (int r = 0; r < 4; ++r) {
                float p = __expf(z[r]);
                lacc += p;
                pk[r] = (_Float16)p;
            }
            *(half4*)&Pt[wave][l16][f * 16 + quad * 4] = pk;
        }

        // ---- P A-frags (same-wave LDS round trip, in-order DS) ----
        half8 pl = *(const half8*)&Pt[wave][l16][quad * 8];
        half8 ph = *(const half8*)&Pt[wave][l16][32 + quad * 8];

        // ---- PV ----
#pragma unroll
        for (int j = 0; j < 4; ++j) {
            half8 vlo = *(const half8*)&Vt[cur][0][j * 16 + l16][fcol];
            half8 vhi = *(const half8*)&Vt[cur][1][j * 16 + l16][fcol];
            o[j] = __builtin_amdgcn_mfma_f32_16x16x32_f16(pl, vlo, o[j], 0, 0, 0);
            o[j] = __builtin_amdgcn_mfma_f32_16x16x32_f16(ph, vhi, o[j], 0, 0, 0);
        }
        cur ^= 1;
    }

    // ---- l: sum quad partials (same q = l16 across quads) ----
    float lr = lacc;
    lr += __shfl_xor(lr, 16);
    lr += __shfl_xor(lr, 32);

    const int b_ = bh / HH;
    const int h_ = bh % HH;
#pragma unroll
    for (int r = 0; r < 4; ++r) {
        float invl = 1.f / __shfl(lr, quad * 4 + r, 16);
        int s_ = q0 + wave * 16 + quad * 4 + r;
        _Float16* orow = ctxh + ((size_t)(b_ * SS + s_)) * DD + h_ * DHH;
#pragma unroll
        for (int j = 0; j < 4; ++j)
            orow[j * 16 + l16] = (_Float16)(o[j][r] * invl);
    }
}

// ---------------------------------------------------------------------------
extern "C" void kernel_launch(void* const* d_in, const int* in_sizes, int n_in,
                              void* d_out, int out_size, void* d_ws, size_t ws_size,
                              hipStream_t stream)
{
    const float* x  = (const float*)d_in[0];
    const float* Wq = (const float*)d_in[1];
    const float* bq = (const float*)d_in[2];
    const float* Wk = (const float*)d_in[3];
    const float* bk = (const float*)d_in[4];
    const float* Wv = (const float*)d_in[5];
    const float* bv = (const float*)d_in[6];
    const float* Wo = (const float*)d_in[7];
    const float* bo = (const float*)d_in[8];
    float* out = (float*)d_out;

    const size_t xe = (size_t)BSS * DD;          // 6,291,456
    const size_t we = (size_t)DD * DD;           // 589,824
    _Float16* Xh   = (_Float16*)d_ws;
    _Float16* Wt   = Xh  + xe;                   // [2304][768]
    _Float16* Wot  = Wt  + (size_t)3 * we;
    _Float16* qhb  = Wot + we;
    _Float16* khb  = qhb + xe;
    _Float16* vtb  = khb + xe;                   // [bh][e][s]
    _Float16* ctxh = vtb + xe;

    prep<<<3072 + 576, 256, 0, stream>>>(x, Xh, Wq, Wk, Wv, Wo, Wt, Wot);

    gemm_qkv_256x128<<<(BSS / 256) * (NQKV / 128), 256, 0, stream>>>(
        Xh, Wt, bq, bk, bv, qhb, khb, vtb);

    dim3 ag(BB * HH, SS / 128);      // (96, 8) = 768 blocks
    attn_f16<<<ag, 512, 0, stream>>>(qhb, khb, vtb, ctxh);

    dim3 gg(BSS / 128, DD / 64);     // (64, 12) = 768 blocks
    gemm_out_f16<<<gg, 256, 0, stream>>>(ctxh, Wot, bo, out);
}